// Round 3
// baseline (885.777 us; speedup 1.0000x reference)
//
#include <hip/hip_runtime.h>

// N=100000 nodes, D=64, P=Q=32, E=3200000 edges.
// Aggregation via deterministic radix partition by dst bucket (R=128 nodes),
// then per-bucket LDS accumulation. No global atomics anywhere.

#define RLOG 7
#define RNODES 128          // nodes per bucket
#define NBLK 160            // partition blocks

__device__ __forceinline__ float softplus_f(float x) {
    return fmaxf(x, 0.0f) + log1pf(expf(-fabsf(x)));
}

__device__ __forceinline__ float bcastf(float v, int k) {
    return __uint_as_float(__builtin_amdgcn_readlane(__float_as_uint(v), k));
}

// ---- 1. per-block bucket histogram: cnt[b*NBLK + blk]
__global__ __launch_bounds__(1024) void bin_count(const int* __restrict__ edst,
                                                  int* __restrict__ cnt,
                                                  int E, int B) {
    __shared__ int lcnt[1024];  // B <= 1024 assumed (782 here)
    int tid = threadIdx.x, blk = blockIdx.x;
    for (int b = tid; b < B; b += 1024) lcnt[b] = 0;
    __syncthreads();
    int chunk = (E + NBLK - 1) / NBLK;
    int start = blk * chunk;
    int end = min(E, start + chunk);
    for (int i = start + tid; i < end; i += 1024)
        atomicAdd(&lcnt[edst[i] >> RLOG], 1);
    __syncthreads();
    for (int b = tid; b < B; b += 1024) cnt[b * NBLK + blk] = lcnt[b];
}

// ---- 2a. per-block partial sums (1024 elems/block)
__global__ __launch_bounds__(1024) void scan_reduce(const int* __restrict__ cnt,
                                                    int* __restrict__ bsum, int M) {
    int idx = blockIdx.x * 1024 + threadIdx.x;
    int v = (idx < M) ? cnt[idx] : 0;
    #pragma unroll
    for (int off = 32; off; off >>= 1) v += __shfl_xor(v, off);
    __shared__ int wtot[16];
    int lane = threadIdx.x & 63, wave = threadIdx.x >> 6;
    if (lane == 0) wtot[wave] = v;
    __syncthreads();
    if (threadIdx.x == 0) {
        int s = 0;
        #pragma unroll
        for (int i = 0; i < 16; ++i) s += wtot[i];
        bsum[blockIdx.x] = s;
    }
}

// ---- 2b. exclusive scan of block sums (nb <= 128)
__global__ void scan_top(int* __restrict__ bsum, int nb) {
    int t = threadIdx.x;
    int v = (t < nb) ? bsum[t] : 0;
    int lane = t & 63, wave = t >> 6;
    int incl = v;
    #pragma unroll
    for (int off = 1; off < 64; off <<= 1) {
        int w = __shfl_up(incl, off);
        if (lane >= off) incl += w;
    }
    __shared__ int wt[2];
    if (lane == 63) wt[wave] = incl;
    __syncthreads();
    int excl = incl - v + ((wave == 1) ? wt[0] : 0);
    if (t < nb) bsum[t] = excl;
}

// ---- 2c. final exclusive scan -> offs
__global__ __launch_bounds__(1024) void scan_final(const int* __restrict__ cnt,
                                                   const int* __restrict__ bsum,
                                                   int* __restrict__ offs, int M) {
    int t = threadIdx.x;
    int idx = blockIdx.x * 1024 + t;
    int lane = t & 63, wave = t >> 6;
    int v = (idx < M) ? cnt[idx] : 0;
    int incl = v;
    #pragma unroll
    for (int off = 1; off < 64; off <<= 1) {
        int w = __shfl_up(incl, off);
        if (lane >= off) incl += w;
    }
    __shared__ int wtot[16];
    if (lane == 63) wtot[wave] = incl;
    __syncthreads();
    int woff = 0;
    for (int i = 0; i < wave; ++i) woff += wtot[i];
    if (idx < M) offs[idx] = bsum[blockIdx.x] + woff + incl - v;
}

// ---- 3. scatter packed entries using LDS cursors (no global atomics)
__global__ __launch_bounds__(1024) void bin_scatter(const int* __restrict__ esrc,
                                                    const int* __restrict__ edst,
                                                    const int* __restrict__ offs,
                                                    int* __restrict__ binned,
                                                    int E, int B) {
    __shared__ int lcur[1024];
    int tid = threadIdx.x, blk = blockIdx.x;
    for (int b = tid; b < B; b += 1024) lcur[b] = offs[b * NBLK + blk];
    __syncthreads();
    int chunk = (E + NBLK - 1) / NBLK;
    int start = blk * chunk;
    int end = min(E, start + chunk);
    for (int i = start + tid; i < end; i += 1024) {
        int d = edst[i];
        int s = esrc[i];
        int b = d >> RLOG;
        int pos = atomicAdd(&lcur[b], 1);
        binned[pos] = ((d & (RNODES - 1)) << 17) | s;
    }
}

// ---- 4. per-bucket aggregation in LDS
__global__ __launch_bounds__(512) void bucket_agg(const float* __restrict__ intensity,
                                                  const int* __restrict__ binned,
                                                  const int* __restrict__ offs,
                                                  float* __restrict__ nbr_mean,
                                                  int E, int N, int B) {
    __shared__ float acc[RNODES * 32];
    __shared__ int scnt[RNODES];
    int tid = threadIdx.x;
    int bucket = blockIdx.x;
    for (int i = tid; i < RNODES * 32; i += 512) acc[i] = 0.0f;
    for (int i = tid; i < RNODES; i += 512) scnt[i] = 0;
    __syncthreads();

    int start = offs[bucket * NBLK];
    int end = (bucket + 1 < B) ? offs[(bucket + 1) * NBLK] : E;

    int lane = tid & 63, wave = tid >> 6;     // 8 waves
    int half = lane >> 5, f = lane & 31;
    int i = start + wave * 2 + half;
    for (; i + 16 < end; i += 32) {
        int eA = binned[i];
        int eB = binned[i + 16];
        float vA = intensity[(size_t)(eA & 131071) * 32 + f];
        float vB = intensity[(size_t)(eB & 131071) * 32 + f];
        atomicAdd(&acc[(eA >> 17) * 32 + f], vA);
        atomicAdd(&acc[(eB >> 17) * 32 + f], vB);
        if (f == 0) {
            atomicAdd(&scnt[eA >> 17], 1);
            atomicAdd(&scnt[eB >> 17], 1);
        }
    }
    if (i < end) {
        int eA = binned[i];
        float vA = intensity[(size_t)(eA & 131071) * 32 + f];
        atomicAdd(&acc[(eA >> 17) * 32 + f], vA);
        if (f == 0) atomicAdd(&scnt[eA >> 17], 1);
    }
    __syncthreads();

    for (int idx = tid; idx < RNODES * 32; idx += 512) {
        int dl = idx >> 5;
        int node = bucket * RNODES + dl;
        if (node < N) {
            float inv = 1.0f / (float)max(scnt[dl], 1);
            nbr_mean[(size_t)node * 32 + (idx & 31)] = acc[idx] * inv;
        }
    }
}

// ---- 5. fused node kernel: weights in registers, readlane broadcast
__global__ __launch_bounds__(256, 2) void node_kernel(
    const float* __restrict__ u, const float* __restrict__ intensity,
    const float* __restrict__ nbr_mean,
    const float* __restrict__ Wf, const float* __restrict__ bf,
    const float* __restrict__ Wg, const float* __restrict__ bg,
    const float* __restrict__ Wz, const float* __restrict__ bz,
    const float* __restrict__ WA, const float* __restrict__ bA,
    float* __restrict__ out, int N) {
    __shared__ float sWf[64 * 65];
    __shared__ float sWg[64 * 65];
    __shared__ float sW3[64 * 65];
    int tid = threadIdx.x;
    for (int idx = tid; idx < 4096; idx += 256) {
        int i = idx >> 6, k = idx & 63;
        sWf[i * 65 + k] = Wf[idx];
        sWg[i * 65 + k] = Wg[idx];
        sW3[i * 65 + k] = (i < 32) ? Wz[i * 64 + k] : WA[(i - 32) * 64 + k];
    }
    __syncthreads();

    int lane = tid & 63;
    int wave = tid >> 6;

    float wf[64], wg[64], w3[64];
    #pragma unroll
    for (int k = 0; k < 64; ++k) {
        wf[k] = sWf[lane * 65 + k];
        wg[k] = sWg[lane * 65 + k];
        w3[k] = sW3[lane * 65 + k];
    }
    float fb = bf[lane];
    float gb = bg[lane];
    float zb = (lane < 32) ? bz[lane] : bA[lane - 32];

    int gwave = blockIdx.x * 4 + wave;
    int wstride = gridDim.x * 4;
    for (int n = gwave; n < N; n += wstride) {
        float uval = u[(size_t)n * 64 + lane];
        float xval = (lane < 32) ? intensity[(size_t)n * 32 + lane]
                                 : nbr_mean[(size_t)n * 32 + (lane - 32)];
        float fA = fb, gA = gb, zA = zb;
        #pragma unroll
        for (int k = 0; k < 64; ++k) {
            float uk = bcastf(uval, k);
            float xk = bcastf(xval, k);
            float in3 = (lane < 32) ? uk : xk;
            fA = fmaf(wf[k], uk, fA);
            gA = fmaf(wg[k], uk, gA);
            zA = fmaf(w3[k], in3, zA);
        }
        float Fu = softplus_f(fA);
        float Gu = softplus_f(gA);
        float zv = (lane < 32) ? tanhf(zA) : fmaxf(zA, 0.0f);
        float du = -Fu * uval + Gu * zv;

        float a = (lane < 32) ? du * uval : 0.0f;
        float b = (lane < 32) ? uval * uval : 0.0f;
        #pragma unroll
        for (int off = 32; off; off >>= 1) {
            a += __shfl_xor(a, off);
            b += __shfl_xor(b, off);
        }
        out[(size_t)n * 64 + lane] = (lane < 32) ? (du - (a / b) * uval) : du;
    }
}

extern "C" void kernel_launch(void* const* d_in, const int* in_sizes, int n_in,
                              void* d_out, int out_size, void* d_ws, size_t ws_size,
                              hipStream_t stream) {
    const float* u         = (const float*)d_in[0];
    const float* intensity = (const float*)d_in[1];
    const int*   esrc      = (const int*)d_in[2];
    const int*   edst      = (const int*)d_in[3];
    const float* Wf        = (const float*)d_in[4];
    const float* bf        = (const float*)d_in[5];
    const float* Wg        = (const float*)d_in[6];
    const float* bg        = (const float*)d_in[7];
    const float* Wz        = (const float*)d_in[8];
    const float* bz        = (const float*)d_in[9];
    const float* WA        = (const float*)d_in[10];
    const float* bA        = (const float*)d_in[11];

    int N = in_sizes[0] / 64;
    int E = in_sizes[2];
    int B = (N + RNODES - 1) / RNODES;          // 782
    int M = B * NBLK;                            // 125120
    int nb = (M + 1023) / 1024;                  // 123 (<=128)

    int* cnt    = (int*)d_ws;                    // M
    int* offs   = cnt + M;                       // M
    int* bsum   = offs + M;                      // 128
    int* binned = bsum + 128;                    // E
    float* nbr_mean = (float*)(binned + E);      // N*32

    bin_count<<<NBLK, 1024, 0, stream>>>(edst, cnt, E, B);
    scan_reduce<<<nb, 1024, 0, stream>>>(cnt, bsum, M);
    scan_top<<<1, 128, 0, stream>>>(bsum, nb);
    scan_final<<<nb, 1024, 0, stream>>>(cnt, bsum, offs, M);
    bin_scatter<<<NBLK, 1024, 0, stream>>>(esrc, edst, offs, binned, E, B);
    bucket_agg<<<B, 512, 0, stream>>>(intensity, binned, offs, nbr_mean, E, N, B);
    node_kernel<<<1024, 256, 0, stream>>>(u, intensity, nbr_mean, Wf, bf, Wg, bg,
                                          Wz, bz, WA, bA, (float*)d_out, N);
}